// Round 1
// baseline (137.402 us; speedup 1.0000x reference)
//
#include <hip/hip_runtime.h>

// Gaussian MMD-like distance:
//   result = mean(f(a,a)) + mean(f(b,b)) - 2*mean(f(a,b)),
//   f elementwise over (i,j,d): exp(-0.5*(m1-m2)^2/(v1+v2)) / sqrt(v1+v2)
// Fused as a single weighted symmetric quadratic form over X=concat(a,b),
// weights +1/-1; only upper-triangular 32x32 tiles computed (off-diag x2).

#define TS 32      // tile rows (pairs tile is TS x TS)
#define NT 64      // tiles per dim: 2048 / TS
#define NPART (NT*NT)

__device__ __forceinline__ float gterm(float2 A, float2 B, float acc) {
  // A = (mu_i[d], var_i[d]),  B = (mu_j[d], var_j[d])
  float vs = A.y + B.y;
  float r  = __builtin_amdgcn_rsqf(vs);          // v_rsq_f32: r = 1/sqrt(vs)
  float dm = A.x - B.x;
  float t  = dm * r;
  float t2 = t * 0.84932180028801904272f;        // sqrt(0.5*log2(e))
  float e  = __builtin_amdgcn_exp2f(-(t2 * t2)); // exp(-0.5*dm^2/vs)
  return fmaf(e, r, acc);
}

__global__ __launch_bounds__(256) void pair_kernel(
    const float* __restrict__ mu_a, const float* __restrict__ lv_a,
    const float* __restrict__ mu_b, const float* __restrict__ lv_b,
    double* __restrict__ partials)
{
  const int bj = blockIdx.x, bi = blockIdx.y;
  const int bid = bi * NT + bj;
  const int tid = threadIdx.x;
  // lower-triangular tiles: write 0 (d_ws is poisoned; every slot must be set)
  if (bi > bj) { if (tid == 0) partials[bid] = 0.0; return; }

  // [side][row][col swizzled]: (mu, var) interleaved. 2*32*128*8B = 64 KiB.
  __shared__ float2 lds[2][TS * 128];

  // tiles never straddle the a/b boundary (32 tiles * 32 rows = 1024)
  const float* muI = (bi < NT/2) ? mu_a + bi*TS*128 : mu_b + (bi - NT/2)*TS*128;
  const float* lvI = (bi < NT/2) ? lv_a + bi*TS*128 : lv_b + (bi - NT/2)*TS*128;
  const float* muJ = (bj < NT/2) ? mu_a + bj*TS*128 : mu_b + (bj - NT/2)*TS*128;
  const float* lvJ = (bj < NT/2) ? lv_a + bj*TS*128 : lv_b + (bj - NT/2)*TS*128;

  // stage: coalesced global reads, var = exp(logvar) via v_exp_f32,
  // XOR-swizzled store col ^ (row & 15) to kill 16-way read conflicts
  for (int s = tid; s < TS * 128; s += 256) {
    int r = s >> 7, c = s & 127;
    int sw = (r << 7) | (c ^ (r & 15));
    lds[0][sw] = make_float2(muI[s],
        __builtin_amdgcn_exp2f(lvI[s] * 1.4426950408889634f));
    lds[1][sw] = make_float2(muJ[s],
        __builtin_amdgcn_exp2f(lvJ[s] * 1.4426950408889634f));
  }
  __syncthreads();

  // 16x16 threads, 2x2 micro-tile: rows {ti, ti+16} x {tj, tj+16}.
  // Address trick: (row<<7) has low 7 bits clear and (d ^ swz) < 128,
  // so lds index = base ^ d with base = (row<<7) ^ swz  (1 XOR per read).
  const int tj = tid & 15, ti = tid >> 4;
  const int aI0 = (ti << 7) ^ ti;
  const int aI1 = ((ti + 16) << 7) ^ ti;   // (ti+16)&15 == ti
  const int aJ0 = (tj << 7) ^ tj;
  const int aJ1 = ((tj + 16) << 7) ^ tj;

  float a00 = 0.f, a01 = 0.f, a10 = 0.f, a11 = 0.f;
  #pragma unroll 4
  for (int d = 0; d < 128; ++d) {
    float2 A0 = lds[0][aI0 ^ d];
    float2 A1 = lds[0][aI1 ^ d];
    float2 B0 = lds[1][aJ0 ^ d];
    float2 B1 = lds[1][aJ1 ^ d];
    a00 = gterm(A0, B0, a00);
    a01 = gterm(A0, B1, a01);
    a10 = gterm(A1, B0, a10);
    a11 = gterm(A1, B1, a11);
  }

  // per-thread f32 partial -> f64 block reduction (cancellation safety)
  double p = (double)((a00 + a01) + (a10 + a11));
  for (int off = 32; off > 0; off >>= 1) p += __shfl_down(p, off, 64);

  __syncthreads();  // all LDS reads done; reuse LDS as f64 scratch
  double* wsum = reinterpret_cast<double*>(&lds[0][0]);
  const int lane = tid & 63, wv = tid >> 6;
  if (lane == 0) wsum[wv] = p;
  __syncthreads();
  if (tid == 0) {
    double t = (wsum[0] + wsum[1]) + (wsum[2] + wsum[3]);
    double w = ((bi < NT/2) == (bj < NT/2)) ? 1.0 : -1.0;  // sign s_I * s_J
    if (bi != bj) w *= 2.0;                                 // symmetry factor
    partials[bid] = w * t;
  }
}

__global__ __launch_bounds__(256) void final_reduce(
    const double* __restrict__ partials, float* __restrict__ out)
{
  __shared__ double wsum[4];
  double s = 0.0;
  for (int i = threadIdx.x; i < NPART; i += 256) s += partials[i];
  for (int off = 32; off > 0; off >>= 1) s += __shfl_down(s, off, 64);
  const int lane = threadIdx.x & 63, wv = threadIdx.x >> 6;
  if (lane == 0) wsum[wv] = s;
  __syncthreads();
  if (threadIdx.x == 0) {
    double t = (wsum[0] + wsum[1]) + (wsum[2] + wsum[3]);
    out[0] = (float)(t * (1.0 / (1024.0 * 1024.0 * 128.0)));
  }
}

extern "C" void kernel_launch(void* const* d_in, const int* in_sizes, int n_in,
                              void* d_out, int out_size, void* d_ws, size_t ws_size,
                              hipStream_t stream) {
  const float* mu_a = (const float*)d_in[0];
  const float* lv_a = (const float*)d_in[1];
  const float* mu_b = (const float*)d_in[2];
  const float* lv_b = (const float*)d_in[3];
  float* out = (float*)d_out;
  double* partials = (double*)d_ws;  // NPART * 8 = 32 KiB

  dim3 grid(NT, NT);
  pair_kernel<<<grid, 256, 0, stream>>>(mu_a, lv_a, mu_b, lv_b, partials);
  final_reduce<<<1, 256, 0, stream>>>(partials, out);
}

// Round 2
// 92.525 us; speedup vs baseline: 1.4850x; 1.4850x over previous
//
#include <hip/hip_runtime.h>

// Gaussian MMD-like distance, fused as one weighted symmetric quadratic form
// over X = concat(a,b) (2048 rows), weights +1/-1:
//   result = (Sum_AA + Sum_BB - 2*Sum_AB) / (1024^2 * 128)
// Only upper-triangular 64x64 tiles are computed (off-diagonal weighted x2).
// Per element: exp(-0.5*(m1-m2)^2/(v1+v2)) * rsqrt(v1+v2)  -> 5 VALU + 2 trans
// (mu pre-scaled by sqrt(0.5*log2(e)) at staging so exp2 needs no extra mul).

#define NTT 32                    // 64-row tiles per dim (2048/64)
#define NTRI (NTT*(NTT+1)/2)      // 528 upper-triangular tiles
#define DSPLIT 2                  // d-dimension split across blocks
#define NPART (NTRI*DSPLIT)       // 1056 partials
#define DCHUNK 32                 // d staged per LDS chunk

#define MUSCALE 0.84932180028801904272f   // sqrt(0.5*log2(e))
#define LOG2E   1.4426950408889634f

__device__ __forceinline__ int tri_off(int b) {
  return b * (2 * NTT + 1 - b) / 2;   // tiles before row b (row b has NTT-b tiles)
}

__device__ __forceinline__ float gterm(float2 A, float2 B, float acc) {
  // A = (mu_i*C, var_i),  B = (mu_j*C, var_j)
  float vs = A.y + B.y;
  float r  = __builtin_amdgcn_rsqf(vs);          // 1/sqrt(vs)        [trans]
  float dm = A.x - B.x;                          // C*(m1-m2)
  float t  = dm * r;
  float e  = __builtin_amdgcn_exp2f(-(t * t));   // exp(-0.5 dm^2/vs) [trans]
  return fmaf(e, r, acc);
}

__global__ __launch_bounds__(256) void pair_kernel(
    const float* __restrict__ mu_a, const float* __restrict__ lv_a,
    const float* __restrict__ mu_b, const float* __restrict__ lv_b,
    double* __restrict__ partials)
{
  // [side][row 64][d DCHUNK swizzled]: (mu*C, var). 2*64*32*8B = 32 KiB.
  __shared__ float2 lds[2][64 * DCHUNK];

  // ---- triangular tile decode: blockIdx.x in [0, 528) -> (bi <= bj) ----
  const int k = blockIdx.x;
  int bi = (int)((2.0 * NTT + 1.0
                  - sqrt((2.0 * NTT + 1.0) * (2.0 * NTT + 1.0) - 8.0 * k)) * 0.5);
  if (bi < 0) bi = 0;
  if (bi > NTT - 1) bi = NTT - 1;
  while (tri_off(bi + 1) <= k) ++bi;
  while (tri_off(bi) > k) --bi;
  const int bj = bi + (k - tri_off(bi));

  // 64-row tiles never straddle the a/b boundary (boundary at tile 16)
  const int rI = bi * 64, rJ = bj * 64;
  const float* muI = (rI < 1024) ? mu_a + rI * 128 : mu_b + (rI - 1024) * 128;
  const float* lvI = (rI < 1024) ? lv_a + rI * 128 : lv_b + (rI - 1024) * 128;
  const float* muJ = (rJ < 1024) ? mu_a + rJ * 128 : mu_b + (rJ - 1024) * 128;
  const float* lvJ = (rJ < 1024) ? lv_a + rJ * 128 : lv_b + (rJ - 1024) * 128;

  const int tid = threadIdx.x;
  const int tj = tid & 15, ti = tid >> 4;    // 16x16 thread grid

  // Swizzled address trick: index = (row<<5) | (d ^ (row&15)) = base ^ d,
  // base = (row<<5) ^ (row&15); rows for this thread: ti+16q / tj+16q.
  int aI[4], aJ[4];
  #pragma unroll
  for (int q = 0; q < 4; ++q) {
    aI[q] = ((ti + 16 * q) << 5) ^ ti;       // (ti+16q)&15 == ti
    aJ[q] = ((tj + 16 * q) << 5) ^ tj;
  }

  float acc[4][4];
  #pragma unroll
  for (int x = 0; x < 4; ++x)
    #pragma unroll
    for (int y = 0; y < 4; ++y) acc[x][y] = 0.f;

  const int dbase0 = blockIdx.y * (128 / DSPLIT);

  for (int c = 0; c < (128 / DSPLIT) / DCHUNK; ++c) {
    const int dbase = dbase0 + c * DCHUNK;
    // ---- stage: coalesced b32 reads, var=exp2(lv*log2e), swizzled store ----
    #pragma unroll
    for (int it = 0; it < (64 * DCHUNK) / 256; ++it) {
      int s = tid + it * 256;
      int r = s >> 5, d = s & 31;
      int sw = (r << 5) | (d ^ (r & 15));
      int g = r * 128 + dbase + d;
      lds[0][sw] = make_float2(muI[g] * MUSCALE,
                               __builtin_amdgcn_exp2f(lvI[g] * LOG2E));
      lds[1][sw] = make_float2(muJ[g] * MUSCALE,
                               __builtin_amdgcn_exp2f(lvJ[g] * LOG2E));
    }
    __syncthreads();

    // ---- compute: 4x4 micro-tile, 8 ds_read_b64 per d for 16 evals ----
    #pragma unroll 4
    for (int d = 0; d < DCHUNK; ++d) {
      float2 A[4], B[4];
      #pragma unroll
      for (int q = 0; q < 4; ++q) {
        A[q] = lds[0][aI[q] ^ d];
        B[q] = lds[1][aJ[q] ^ d];
      }
      #pragma unroll
      for (int x = 0; x < 4; ++x)
        #pragma unroll
        for (int y = 0; y < 4; ++y)
          acc[x][y] = gterm(A[x], B[y], acc[x][y]);
    }
    __syncthreads();
  }

  // ---- reduction: f32 pairwise -> f64 block sum (cancellation safety) ----
  float s00 = (acc[0][0] + acc[0][1]) + (acc[0][2] + acc[0][3]);
  float s01 = (acc[1][0] + acc[1][1]) + (acc[1][2] + acc[1][3]);
  float s10 = (acc[2][0] + acc[2][1]) + (acc[2][2] + acc[2][3]);
  float s11 = (acc[3][0] + acc[3][1]) + (acc[3][2] + acc[3][3]);
  double p = (double)((s00 + s01) + (s10 + s11));
  for (int off = 32; off > 0; off >>= 1) p += __shfl_down(p, off, 64);

  __syncthreads();   // LDS reads done; reuse as f64 scratch
  double* wsum = reinterpret_cast<double*>(&lds[0][0]);
  if ((tid & 63) == 0) wsum[tid >> 6] = p;
  __syncthreads();
  if (tid == 0) {
    double t = (wsum[0] + wsum[1]) + (wsum[2] + wsum[3]);
    double w = ((bi < 16) == (bj < 16)) ? 1.0 : -1.0;   // sign s_I * s_J
    if (bi != bj) w *= 2.0;                              // symmetry factor
    partials[blockIdx.y * NTRI + blockIdx.x] = w * t;
  }
}

__global__ __launch_bounds__(256) void final_reduce(
    const double* __restrict__ partials, float* __restrict__ out)
{
  __shared__ double wsum[4];
  double s = 0.0;
  for (int i = threadIdx.x; i < NPART; i += 256) s += partials[i];
  for (int off = 32; off > 0; off >>= 1) s += __shfl_down(s, off, 64);
  if ((threadIdx.x & 63) == 0) wsum[threadIdx.x >> 6] = s;
  __syncthreads();
  if (threadIdx.x == 0) {
    double t = (wsum[0] + wsum[1]) + (wsum[2] + wsum[3]);
    out[0] = (float)(t * (1.0 / (1024.0 * 1024.0 * 128.0)));
  }
}

extern "C" void kernel_launch(void* const* d_in, const int* in_sizes, int n_in,
                              void* d_out, int out_size, void* d_ws, size_t ws_size,
                              hipStream_t stream) {
  const float* mu_a = (const float*)d_in[0];
  const float* lv_a = (const float*)d_in[1];
  const float* mu_b = (const float*)d_in[2];
  const float* lv_b = (const float*)d_in[3];
  float* out = (float*)d_out;
  double* partials = (double*)d_ws;   // NPART * 8 = 8.25 KiB

  dim3 grid(NTRI, DSPLIT);
  pair_kernel<<<grid, 256, 0, stream>>>(mu_a, lv_a, mu_b, lv_b, partials);
  final_reduce<<<1, 256, 0, stream>>>(partials, out);
}

// Round 3
// 79.896 us; speedup vs baseline: 1.7198x; 1.1581x over previous
//
#include <hip/hip_runtime.h>

// Gaussian MMD distance as one weighted symmetric quadratic form over
// X = concat(a,b), weights +1/-1; upper-triangular 64x64 tiles only
// (off-diagonal x2). Per element: exp(-0.5*dm^2/vs) * rsqrt(vs).
// d-dimension processed in PAIRS (SoA float4 = mu0,mu1,var0,var1) so the
// 5 regular VALU ops/element form packable float2 pairs; 2 trans/element
// (v_rsq, v_exp) is the floor.

#define NTT 32                    // 64-row tiles per dim (2048/64)
#define NTRI (NTT*(NTT+1)/2)      // 528 upper-triangular tiles
#define DSPLIT 8                  // d split: each block does 16 d = 8 pairs
#define NPART (NTRI*DSPLIT)       // 4224 partials
#define PAIRS 8                   // d-pairs staged per block

#define MUSCALE 0.84932180028801904272f   // sqrt(0.5*log2(e))
#define LOG2E   1.4426950408889634f

__device__ __forceinline__ int tri_off(int b) {
  return b * (2 * NTT + 1 - b) / 2;
}

__global__ __launch_bounds__(256, 6) void pair_kernel(
    const float* __restrict__ mu_a, const float* __restrict__ lv_a,
    const float* __restrict__ mu_b, const float* __restrict__ lv_b,
    double* __restrict__ partials)
{
  // [side][row 64][pair 8]: float4 (mu0*C, mu1*C, var0, var1). 16 KiB.
  __shared__ float4 lds[2][64 * PAIRS];

  // ---- triangular tile decode: blockIdx.x in [0,528) -> (bi <= bj) ----
  const int k = blockIdx.x;
  int bi = (int)((2.0 * NTT + 1.0
                  - sqrt((2.0 * NTT + 1.0) * (2.0 * NTT + 1.0) - 8.0 * k)) * 0.5);
  if (bi < 0) bi = 0;
  if (bi > NTT - 1) bi = NTT - 1;
  while (tri_off(bi + 1) <= k) ++bi;
  while (tri_off(bi) > k) --bi;
  const int bj = bi + (k - tri_off(bi));

  const int rI = bi * 64, rJ = bj * 64;     // never straddle a/b boundary
  const float* muI = (rI < 1024) ? mu_a + rI * 128 : mu_b + (rI - 1024) * 128;
  const float* lvI = (rI < 1024) ? lv_a + rI * 128 : lv_b + (rI - 1024) * 128;
  const float* muJ = (rJ < 1024) ? mu_a + rJ * 128 : mu_b + (rJ - 1024) * 128;
  const float* lvJ = (rJ < 1024) ? lv_a + rJ * 128 : lv_b + (rJ - 1024) * 128;

  const int tid = threadIdx.x;
  const int dbase = blockIdx.y * (128 / DSPLIT);   // 16 d's per block

  // ---- stage: 1024 float4 slots, 4 per thread, coalesced float2 loads ----
  // swizzled slot: (row<<3) ^ (row&7) ^ p  (p < 8, low 3 bits free)
  #pragma unroll
  for (int it = 0; it < 4; ++it) {
    int s = tid + it * 256;            // [0, 1024)
    int side = s >> 9, rem = s & 511;
    int row = rem >> 3, p = rem & 7;
    const float2* m2 = (const float2*)((side == 0) ? muI : muJ);
    const float2* l2 = (const float2*)((side == 0) ? lvI : lvJ);
    int g = row * 64 + (dbase >> 1) + p;
    float2 m = m2[g], l = l2[g];
    lds[side][(row << 3) ^ (row & 7) ^ p] =
        make_float4(m.x * MUSCALE, m.y * MUSCALE,
                    __builtin_amdgcn_exp2f(l.x * LOG2E),
                    __builtin_amdgcn_exp2f(l.y * LOG2E));
  }
  __syncthreads();

  // ---- compute: 16x16 threads, 4x4 rows x 2 d's per ds_read_b128 ----
  const int tj = tid & 15, ti = tid >> 4;
  int baseI[4], baseJ[4];
  #pragma unroll
  for (int q = 0; q < 4; ++q) {
    baseI[q] = ((ti + 16 * q) << 3) ^ (ti & 7);   // (ti+16q)&7 == ti&7
    baseJ[q] = ((tj + 16 * q) << 3) ^ (tj & 7);
  }

  float acc[4][4];
  #pragma unroll
  for (int x = 0; x < 4; ++x)
    #pragma unroll
    for (int y = 0; y < 4; ++y) acc[x][y] = 0.f;

  #pragma unroll
  for (int p = 0; p < PAIRS; ++p) {
    float4 A[4], B[4];
    #pragma unroll
    for (int q = 0; q < 4; ++q) {
      A[q] = lds[0][baseI[q] ^ p];
      B[q] = lds[1][baseJ[q] ^ p];
    }
    #pragma unroll
    for (int x = 0; x < 4; ++x)
      #pragma unroll
      for (int y = 0; y < 4; ++y) {
        // two d-elements, pairwise ops sit in adjacent regs (pk-able)
        float v0 = A[x].z + B[y].z,  v1 = A[x].w + B[y].w;
        float r0 = __builtin_amdgcn_rsqf(v0);
        float r1 = __builtin_amdgcn_rsqf(v1);
        float d0 = A[x].x - B[y].x,  d1 = A[x].y - B[y].y;
        float t0 = d0 * r0,          t1 = d1 * r1;
        float e0 = __builtin_amdgcn_exp2f(-(t0 * t0));
        float e1 = __builtin_amdgcn_exp2f(-(t1 * t1));
        acc[x][y] = fmaf(e0, r0, fmaf(e1, r1, acc[x][y]));
      }
  }

  // ---- reduction: f32 pairwise -> f64 (cancellation safety) ----
  float s0 = 0.f, s1 = 0.f;
  #pragma unroll
  for (int x = 0; x < 4; ++x) {
    s0 += acc[x][0] + acc[x][1];
    s1 += acc[x][2] + acc[x][3];
  }
  double pdb = (double)s0 + (double)s1;
  for (int off = 32; off > 0; off >>= 1) pdb += __shfl_down(pdb, off, 64);

  __syncthreads();   // LDS reads done; reuse as f64 scratch
  double* wsum = reinterpret_cast<double*>(&lds[0][0]);
  if ((tid & 63) == 0) wsum[tid >> 6] = pdb;
  __syncthreads();
  if (tid == 0) {
    double t = (wsum[0] + wsum[1]) + (wsum[2] + wsum[3]);
    double w = ((bi < 16) == (bj < 16)) ? 1.0 : -1.0;   // sign s_I*s_J
    if (bi != bj) w *= 2.0;                              // symmetry factor
    partials[blockIdx.y * NTRI + blockIdx.x] = w * t;
  }
}

__global__ __launch_bounds__(256) void final_reduce(
    const double* __restrict__ partials, float* __restrict__ out)
{
  __shared__ double wsum[4];
  double s = 0.0;
  for (int i = threadIdx.x; i < NPART; i += 256) s += partials[i];
  for (int off = 32; off > 0; off >>= 1) s += __shfl_down(s, off, 64);
  if ((threadIdx.x & 63) == 0) wsum[threadIdx.x >> 6] = s;
  __syncthreads();
  if (threadIdx.x == 0) {
    double t = (wsum[0] + wsum[1]) + (wsum[2] + wsum[3]);
    out[0] = (float)(t * (1.0 / (1024.0 * 1024.0 * 128.0)));
  }
}

extern "C" void kernel_launch(void* const* d_in, const int* in_sizes, int n_in,
                              void* d_out, int out_size, void* d_ws, size_t ws_size,
                              hipStream_t stream) {
  const float* mu_a = (const float*)d_in[0];
  const float* lv_a = (const float*)d_in[1];
  const float* mu_b = (const float*)d_in[2];
  const float* lv_b = (const float*)d_in[3];
  float* out = (float*)d_out;
  double* partials = (double*)d_ws;   // NPART*8 = 33 KiB scratch

  dim3 grid(NTRI, DSPLIT);
  pair_kernel<<<grid, 256, 0, stream>>>(mu_a, lv_a, mu_b, lv_b, partials);
  final_reduce<<<1, 256, 0, stream>>>(partials, out);
}

// Round 4
// 67.227 us; speedup vs baseline: 2.0438x; 1.1884x over previous
//
#include <hip/hip_runtime.h>

// Gaussian MMD distance as one weighted symmetric quadratic form over
// X = concat(a,b), weights +1/-1; upper-triangular 64x64 tiles only
// (off-diagonal x2). Per element: exp(-0.5*dm^2/vs) * rsqrt(vs).
// d processed in PAIRS via float2 arithmetic -> v_pk_{add,mul,fma}_f32
// (gfx90a+ packed f32), so the 5 regular VALU ops per element cost half
// an issue slot each; 2 transcendentals/element (v_rsq, v_exp) are the floor.

#define NTT 32                    // 64-row tiles per dim (2048/64)
#define NTRI (NTT*(NTT+1)/2)      // 528 upper-triangular tiles
#define DSPLIT 8                  // d split: each block does 16 d = 8 pairs
#define NPART (NTRI*DSPLIT)       // 4224 partials
#define PAIRS 8                   // d-pairs staged per block

#define MUSCALE 0.84932180028801904272f   // sqrt(0.5*log2(e))
#define LOG2E   1.4426950408889634f

__device__ __forceinline__ int tri_off(int b) {
  return b * (2 * NTT + 1 - b) / 2;
}

__global__ __launch_bounds__(256, 6) void pair_kernel(
    const float* __restrict__ mu_a, const float* __restrict__ lv_a,
    const float* __restrict__ mu_b, const float* __restrict__ lv_b,
    double* __restrict__ partials)
{
  // [side][row 64][pair 8]: float4 (mu0*C, mu1*C, var0, var1). 16 KiB.
  __shared__ float4 lds[2][64 * PAIRS];

  // ---- triangular tile decode: blockIdx.x in [0,528) -> (bi <= bj) ----
  const int k = blockIdx.x;
  int bi = (int)((2.0 * NTT + 1.0
                  - sqrt((2.0 * NTT + 1.0) * (2.0 * NTT + 1.0) - 8.0 * k)) * 0.5);
  if (bi < 0) bi = 0;
  if (bi > NTT - 1) bi = NTT - 1;
  while (tri_off(bi + 1) <= k) ++bi;
  while (tri_off(bi) > k) --bi;
  const int bj = bi + (k - tri_off(bi));

  const int rI = bi * 64, rJ = bj * 64;     // never straddle a/b boundary
  const float* muI = (rI < 1024) ? mu_a + rI * 128 : mu_b + (rI - 1024) * 128;
  const float* lvI = (rI < 1024) ? lv_a + rI * 128 : lv_b + (rI - 1024) * 128;
  const float* muJ = (rJ < 1024) ? mu_a + rJ * 128 : mu_b + (rJ - 1024) * 128;
  const float* lvJ = (rJ < 1024) ? lv_a + rJ * 128 : lv_b + (rJ - 1024) * 128;

  const int tid = threadIdx.x;
  const int dbase = blockIdx.y * (128 / DSPLIT);   // 16 d's per block

  // ---- stage: 1024 float4 slots, 4 per thread, coalesced float2 loads ----
  // swizzled slot: (row<<3) ^ (row&7) ^ p  (p < 8, low 3 bits free)
  #pragma unroll
  for (int it = 0; it < 4; ++it) {
    int s = tid + it * 256;            // [0, 1024)
    int side = s >> 9, rem = s & 511;
    int row = rem >> 3, p = rem & 7;
    const float2* m2 = (const float2*)((side == 0) ? muI : muJ);
    const float2* l2 = (const float2*)((side == 0) ? lvI : lvJ);
    int g = row * 64 + (dbase >> 1) + p;
    float2 m = m2[g], l = l2[g];
    lds[side][(row << 3) ^ (row & 7) ^ p] =
        make_float4(m.x * MUSCALE, m.y * MUSCALE,
                    __builtin_amdgcn_exp2f(l.x * LOG2E),
                    __builtin_amdgcn_exp2f(l.y * LOG2E));
  }
  __syncthreads();

  // ---- compute: 16x16 threads, 4x4 rows x 2 d's per ds_read_b128 ----
  const int tj = tid & 15, ti = tid >> 4;
  int baseI[4], baseJ[4];
  #pragma unroll
  for (int q = 0; q < 4; ++q) {
    baseI[q] = ((ti + 16 * q) << 3) ^ (ti & 7);   // (ti+16q)&7 == ti&7
    baseJ[q] = ((tj + 16 * q) << 3) ^ (tj & 7);
  }

  float2 acc[4][4];
  #pragma unroll
  for (int x = 0; x < 4; ++x)
    #pragma unroll
    for (int y = 0; y < 4; ++y) acc[x][y] = make_float2(0.f, 0.f);

  #pragma unroll
  for (int p = 0; p < PAIRS; ++p) {
    float4 A[4], B[4];
    #pragma unroll
    for (int q = 0; q < 4; ++q) {
      A[q] = lds[0][baseI[q] ^ p];
      B[q] = lds[1][baseJ[q] ^ p];
    }
    #pragma unroll
    for (int x = 0; x < 4; ++x) {
      const float2 Amu = make_float2(A[x].x, A[x].y);
      const float2 Avr = make_float2(A[x].z, A[x].w);
      #pragma unroll
      for (int y = 0; y < 4; ++y) {
        const float2 Bmu = make_float2(B[y].x, B[y].y);
        const float2 Bvr = make_float2(B[y].z, B[y].w);
        float2 vs = Avr + Bvr;                       // v_pk_add_f32
        float2 r;
        r.x = __builtin_amdgcn_rsqf(vs.x);           // v_rsq_f32 [trans]
        r.y = __builtin_amdgcn_rsqf(vs.y);
        float2 dm = Amu - Bmu;                       // v_pk_add_f32 (neg)
        float2 t  = dm * r;                          // v_pk_mul_f32
        float2 m  = t * t;                           // v_pk_mul_f32
        float2 e;
        e.x = __builtin_amdgcn_exp2f(-m.x);          // v_exp_f32 [trans], neg folds
        e.y = __builtin_amdgcn_exp2f(-m.y);
        acc[x][y] += e * r;                          // v_pk_fma_f32
      }
    }
  }

  // ---- reduction: f32 pairwise -> f64 (cancellation safety) ----
  float2 s0 = make_float2(0.f, 0.f), s1 = make_float2(0.f, 0.f);
  #pragma unroll
  for (int x = 0; x < 4; ++x) {
    s0 += acc[x][0] + acc[x][1];
    s1 += acc[x][2] + acc[x][3];
  }
  double pdb = (double)(s0.x + s1.x) + (double)(s0.y + s1.y);
  for (int off = 32; off > 0; off >>= 1) pdb += __shfl_down(pdb, off, 64);

  __syncthreads();   // LDS reads done; reuse as f64 scratch
  double* wsum = reinterpret_cast<double*>(&lds[0][0]);
  if ((tid & 63) == 0) wsum[tid >> 6] = pdb;
  __syncthreads();
  if (tid == 0) {
    double t = (wsum[0] + wsum[1]) + (wsum[2] + wsum[3]);
    double w = ((bi < 16) == (bj < 16)) ? 1.0 : -1.0;   // sign s_I*s_J
    if (bi != bj) w *= 2.0;                              // symmetry factor
    partials[blockIdx.y * NTRI + blockIdx.x] = w * t;
  }
}

__global__ __launch_bounds__(256) void final_reduce(
    const double* __restrict__ partials, float* __restrict__ out)
{
  __shared__ double wsum[4];
  double s = 0.0;
  for (int i = threadIdx.x; i < NPART; i += 256) s += partials[i];
  for (int off = 32; off > 0; off >>= 1) s += __shfl_down(s, off, 64);
  if ((threadIdx.x & 63) == 0) wsum[threadIdx.x >> 6] = s;
  __syncthreads();
  if (threadIdx.x == 0) {
    double t = (wsum[0] + wsum[1]) + (wsum[2] + wsum[3]);
    out[0] = (float)(t * (1.0 / (1024.0 * 1024.0 * 128.0)));
  }
}

extern "C" void kernel_launch(void* const* d_in, const int* in_sizes, int n_in,
                              void* d_out, int out_size, void* d_ws, size_t ws_size,
                              hipStream_t stream) {
  const float* mu_a = (const float*)d_in[0];
  const float* lv_a = (const float*)d_in[1];
  const float* mu_b = (const float*)d_in[2];
  const float* lv_b = (const float*)d_in[3];
  float* out = (float*)d_out;
  double* partials = (double*)d_ws;   // NPART*8 = 33 KiB scratch

  dim3 grid(NTRI, DSPLIT);
  pair_kernel<<<grid, 256, 0, stream>>>(mu_a, lv_a, mu_b, lv_b, partials);
  final_reduce<<<1, 256, 0, stream>>>(partials, out);
}